// Round 7
// baseline (133.405 us; speedup 1.0000x reference)
//
#include <hip/hip_runtime.h>

#define NQ 6
#define HID 32
#define SNAPS 16
#define BATCH 1024
#define FSTRIDE 24       // floats per feature vector
#define FTOT 384         // 16 * 24
#define KSTR 24          // K-matrix LDS stride (16B-aligned, <=2-way conflicts = free)
#define KF   192         // per-f block: 8 cols/rows x 24

typedef float vfloat4 __attribute__((ext_vector_type(4)));   // for nontemporal stores

__device__ __forceinline__ float sigm_f(float x) { return 1.0f / (1.0f + __expf(-x)); }
__device__ __forceinline__ float tanh_f(float x) { return 1.0f - 2.0f / (__expf(2.0f * x) + 1.0f); }

__device__ __forceinline__ void rc_entry(float g, float b0, float b1, float b2,
                                         int i, int j, float& re, float& im) {
    // rc = (I + 3*shadow*B)/2, B = b0*sx + b1*sy + b2*sz ; g = 1.5*shadow
    if (i == j) { re = 0.5f + (i ? -g * b2 : g * b2); im = 0.0f; }
    else        { re = g * b0;  im = (i ? g * b1 : -g * b1); }
}

// One block per batch element. Phase 1: waves 0-1 run the 15-step LSTM
// (1 gate row per lane, weights in VGPRs; projection weights in LDS to keep
// persistent regs ~58 and avoid scratch spills under the 128-VGPR cap).
// Phase 2: all 4 waves build KA/KB and do the rank-16 complex accumulation.
__global__ __launch_bounds__(256, 2)
void fused_kernel(const float* __restrict__ snapshot,   // (B,6)
                  const float* __restrict__ bcv,        // (B,6,3)
                  const float* __restrict__ h0,         // (B,32)
                  const float* __restrict__ c0,         // (B,32)
                  const float* __restrict__ W_ih,       // (128,24)
                  const float* __restrict__ W_hh,       // (128,32)
                  const float* __restrict__ b_ih,       // (128)
                  const float* __restrict__ b_hh,       // (128)
                  const float* __restrict__ Wp,         // (6,32,3)
                  const float* __restrict__ bp,         // (6,3)
                  float* __restrict__ out,              // (B,2,64,64)
                  float* __restrict__ out_tail)         // (B,6,3)
{
    __shared__ __align__(16) float sKA[16 * KF];   // 3072
    __shared__ __align__(16) float sKB[16 * KF];   // 3072
    __shared__ __align__(16) float feat[FTOT];     // 384
    __shared__ __align__(16) float sh[HID];        // 32
    __shared__ __align__(16) float sg[128];        // gate pre-activations
    __shared__ __align__(16) float sWpT[18 * 36];  // WpT[(3q+s)][h], padded stride 36
    __shared__ float sbp[18];

    const int b = blockIdx.x;
    const int t = threadIdx.x;

    // ---- phase-1 register state: ONLY the gate-row weights (56 regs) ----
    float4 wih[6], whh[8];
    float bias = 0.0f, c = 0.0f;
    if (t < 128) {
        const float4* p = (const float4*)(W_ih + t * 24);
        #pragma unroll
        for (int k = 0; k < 6; ++k) wih[k] = p[k];
        const float4* q = (const float4*)(W_hh + t * 32);
        #pragma unroll
        for (int k = 0; k < 8; ++k) whh[k] = q[k];
        bias = b_ih[t] + b_hh[t];
    }
    // projection weights -> LDS (transposed, padded)
    for (int idx = t; idx < NQ * HID * 3; idx += 256) {
        int q = idx / 96, r = idx - q * 96;
        int h = r / 3, s = r - h * 3;
        sWpT[(q * 3 + s) * 36 + h] = Wp[idx];
    }
    if (t < 18) sbp[t] = bp[t];
    if (t < 32) { c = c0[b * 32 + t]; sh[t] = h0[b * 32 + t]; }
    if (t < 24) feat[t] = (t < 6) ? snapshot[b * 6 + t] : bcv[b * 18 + (t - 6)];
    __syncthreads();

    // ---- LSTM chain: 15 steps, 2 block barriers/step ----
    for (int step = 0; step < SNAPS - 1; ++step) {
        if (t < 128) {
            const float4* x4 = (const float4*)(feat + step * FSTRIDE);  // broadcast
            const float4* h4 = (const float4*)sh;
            float ga = bias, gb = 0.0f;
            #pragma unroll
            for (int k = 0; k < 6; ++k) {
                float4 xq = x4[k];
                ga += xq.x * wih[k].x + xq.y * wih[k].y;
                gb += xq.z * wih[k].z + xq.w * wih[k].w;
            }
            #pragma unroll
            for (int k = 0; k < 8; ++k) {
                float4 hq = h4[k];
                ga += hq.x * whh[k].x + hq.y * whh[k].y;
                gb += hq.z * whh[k].z + hq.w * whh[k].w;
            }
            sg[t] = ga + gb;
        }
        __syncthreads();

        if (t < 64) {   // wave 0 only: activation + projection + softmax
            if (t < 32) {
                float gi = sg[t], gf = sg[32 + t], gg = sg[64 + t], go = sg[96 + t];
                c = sigm_f(gf) * c + sigm_f(gi) * tanh_f(gg);
                sh[t] = sigm_f(go) * tanh_f(c);
            }
            __builtin_amdgcn_wave_barrier();   // order in-wave DS: sh write -> reads below
            // projection: lanes 0..17 read their WpT row from LDS (float4)
            int row = (t < 18) ? t : 17;
            const float4* wr  = (const float4*)&sWpT[row * 36];
            const float4* h4b = (const float4*)sh;
            float la = (t < 18) ? sbp[row] : 0.0f, lb = 0.0f;
            #pragma unroll
            for (int k = 0; k < 8; ++k) {
                float4 hq = h4b[k], wq = wr[k];
                la += hq.x * wq.x + hq.y * wq.y;
                lb += hq.z * wq.z + hq.w * wq.w;
            }
            float logit = la + lb;
            int q3 = 3 * (t < 6 ? t : 0);
            float l0 = __shfl(logit, q3), l1 = __shfl(logit, q3 + 1), l2 = __shfl(logit, q3 + 2);
            if (t < 6) {
                float m = fmaxf(l0, fmaxf(l1, l2));
                float e0 = __expf(l0 - m), e1 = __expf(l1 - m), e2 = __expf(l2 - m);
                float inv = 1.0f / (e0 + e1 + e2);
                float p0 = e0 * inv, p1 = e1 * inv, p2 = e2 * inv;
                float snap = p0 * p0 + p1 * p1 + p2 * p2;  // tr(M rho Mdag)=sum p^2 (rho unused)
                float* fd = feat + (step + 1) * FSTRIDE;
                fd[t] = snap;
                fd[6 + 3 * t]     = p0;
                fd[6 + 3 * t + 1] = p1;
                fd[6 + 3 * t + 2] = p2;
            }
        }
        __syncthreads();
    }

    // ---- tail output: bv of last feature = final probs ----
    if (t < 18) out_tail[b * 18 + t] = feat[15 * FSTRIDE + 6 + t];

    // ---- build KA/KB: 2048 entries, 8 per thread ----
    for (int n = t; n < 2048; n += 256) {
        int f = n >> 7, r = n & 127;
        int half = r >> 6, a = r & 63;
        const float* fx = &feat[f * FSTRIDE];
        int i0 = (a >> 5) & 1, i1 = (a >> 4) & 1, i2 = (a >> 3) & 1;
        int j0 = (a >> 2) & 1, j1 = (a >> 1) & 1, j2 = a & 1;
        int q = 3 * half;
        float g0 = 1.5f * fx[q], g1 = 1.5f * fx[q + 1], g2 = 1.5f * fx[q + 2];
        const float* bb = fx + 6 + 3 * q;
        float r0, m0, r1, m1, r2, m2;
        rc_entry(g0, bb[0], bb[1], bb[2], i0, j0, r0, m0);
        rc_entry(g1, bb[3], bb[4], bb[5], i1, j1, r1, m1);
        rc_entry(g2, bb[6], bb[7], bb[8], i2, j2, r2, m2);
        float pr = r0 * r1 - m0 * m1, pi = r0 * m1 + m0 * r1;
        float qr = pr * r2 - pi * m2, qi = pr * m2 + pi * r2;
        int row = a >> 3, col = a & 7;
        if (half == 0) {
            // KA: col-major, rows grouped by parity (even at [0..7], odd at [8..15])
            int off = f * KF + col * KSTR + ((row & 1) ? (7 + row) : row);
            sKA[off] = qr; sKA[off + 1] = qi;
        } else {
            int off = f * KF + row * KSTR + 2 * col;
            sKB[off] = qr; sKB[off + 1] = qi;
        }
    }
    __syncthreads();

    // ---- accumulate: out[i][j] = (1/16) sum_f KA[i>>3][j>>3] * KB[i&7][j&7]
    // thread t: u=t&15, v=t>>4; i = v+16e (e<4), j = 4u+d (d<4)
    const int u = t & 15, v = t >> 4;
    const float* baseA = sKA + (u >> 1) * KSTR + 8 * (v >> 3);   // col jA, parity group
    const float* baseB = sKB + (v & 7) * KSTR + 8 * (u & 1);     // row iB, col group
    float accr[4][4], acci[4][4];
    #pragma unroll
    for (int e = 0; e < 4; ++e)
        #pragma unroll
        for (int d = 0; d < 4; ++d) { accr[e][d] = 0.0f; acci[e][d] = 0.0f; }

    #pragma unroll 2   // keep hoisted LDS loads within the 128-VGPR budget (no scratch!)
    for (int f = 0; f < SNAPS; ++f) {
        float4 A0 = *(const float4*)(baseA + f * KF);
        float4 A1 = *(const float4*)(baseA + f * KF + 4);
        float4 B0 = *(const float4*)(baseB + f * KF);
        float4 B1 = *(const float4*)(baseB + f * KF + 4);
        float ar[4] = {A0.x, A0.z, A1.x, A1.z};    // iA = 2e + (v>>3)
        float ai[4] = {A0.y, A0.w, A1.y, A1.w};
        float br[4] = {B0.x, B0.z, B1.x, B1.z};    // jB = 4(u&1) + d
        float bi[4] = {B0.y, B0.w, B1.y, B1.w};
        #pragma unroll
        for (int e = 0; e < 4; ++e)
            #pragma unroll
            for (int d = 0; d < 4; ++d) {
                accr[e][d] += ar[e] * br[d] - ai[e] * bi[d];
                acci[e][d] += ar[e] * bi[d] + ai[e] * br[d];
            }
    }

    const float s = 1.0f / 16.0f;
    float* outb = out + (size_t)b * 8192;
    #pragma unroll
    for (int e = 0; e < 4; ++e) {
        int i = v + 16 * e;
        vfloat4 r4 = { accr[e][0] * s, accr[e][1] * s, accr[e][2] * s, accr[e][3] * s };
        vfloat4 i4 = { acci[e][0] * s, acci[e][1] * s, acci[e][2] * s, acci[e][3] * s };
        __builtin_nontemporal_store(r4, (vfloat4*)(outb + i * 64 + 4 * u));
        __builtin_nontemporal_store(i4, (vfloat4*)(outb + 4096 + i * 64 + 4 * u));
    }
}

extern "C" void kernel_launch(void* const* d_in, const int* in_sizes, int n_in,
                              void* d_out, int out_size, void* d_ws, size_t ws_size,
                              hipStream_t stream) {
    const float* snapshot = (const float*)d_in[0];
    const float* bcv      = (const float*)d_in[1];
    // d_in[2] = rho — unused: tr(M rho M^dag) = (sum_s p_s^2) tr(rho), tr(rho)=1
    const float* h0       = (const float*)d_in[3];
    const float* c0       = (const float*)d_in[4];
    const float* W_ih     = (const float*)d_in[5];
    const float* W_hh     = (const float*)d_in[6];
    const float* b_ih     = (const float*)d_in[7];
    const float* b_hh     = (const float*)d_in[8];
    const float* Wp       = (const float*)d_in[9];
    const float* bp       = (const float*)d_in[10];
    // d_in[11], d_in[12] = basis_r, basis_i — folded into rc_entry
    float* out = (float*)d_out;

    fused_kernel<<<BATCH, 256, 0, stream>>>(
        snapshot, bcv, h0, c0, W_ih, W_hh, b_ih, b_hh, Wp, bp,
        out, out + (size_t)BATCH * 8192);
}